// Round 12
// baseline (242.895 us; speedup 1.0000x reference)
//
#include <hip/hip_runtime.h>
#include <cstdint>
#include <cstddef>

typedef __bf16 bf16;
typedef __bf16 bf16x8 __attribute__((ext_vector_type(8)));
typedef float  f32x4 __attribute__((ext_vector_type(4)));
typedef float  f32x16 __attribute__((ext_vector_type(16)));
typedef int    i32x4 __attribute__((ext_vector_type(4)));
typedef int    i32x8 __attribute__((ext_vector_type(8)));

#define MFMA16(a, b, c) __builtin_amdgcn_mfma_f32_16x16x32_bf16((a), (b), (c), 0, 0, 0)
// MX-scaled fp8 MFMA, both scales = 1.0 (E8M0 127): fmt a=b=0 (fp8 e4m3)
#define MFMA_MX(a, b, c) \
    __builtin_amdgcn_mfma_scale_f32_32x32x64_f8f6f4((a), (b), (c), 0, 0, 0, 0x7F, 0, 0x7F)

#if __has_builtin(__builtin_amdgcn_exp2f)
#define EXP2(x) __builtin_amdgcn_exp2f(x)
#else
#define EXP2(x) exp2f(x)
#endif

// float -> fp8 e4m3 (OCP), RNE, single byte
__device__ __forceinline__ uint8_t to_fp8(float v) {
    return (uint8_t)(__builtin_amdgcn_cvt_pk_fp8_f32(v, v, 0, false) & 0xff);
}

// 32B load as two 16B vector loads (LDS: 2x ds_read_b128; global: 2x dwordx4)
__device__ __forceinline__ i32x8 ld32(const void* p) {
    i32x4 a = *(const i32x4*)p;
    i32x4 b = *(const i32x4*)((const char*)p + 16);
    i32x8 r;
    r[0] = a[0]; r[1] = a[1]; r[2] = a[2]; r[3] = a[3];
    r[4] = b[0]; r[5] = b[1]; r[6] = b[2]; r[7] = b[3];
    return r;
}

// async global->LDS, 16B per lane. LDS dest is wave-uniform base + lane*16.
__device__ __forceinline__ void gload16(const void* g, void* l) {
    __builtin_amdgcn_global_load_lds(
        (const __attribute__((address_space(1))) unsigned int*)g,
        (__attribute__((address_space(3))) unsigned int*)l,
        16, 0, 0);
}

// ---------------------------------------------------------------------------
// RMSNorm + (blocks 256..383) weight fp32->bf16 conversion.
// Blocks 0..255: 64 tokens each; wave w owns channel quarter [96w,96w+96),
// lane l owns token p0+l; values live in registers. Output goes through an
// LDS [64][392] transpose tile so the xn write is fully coalesced.
// x [4][384][4096] fp32 -> xn [16384][384] bf16.
// ---------------------------------------------------------------------------
__global__ __launch_bounds__(256) void norm_kernel(
    const float* __restrict__ x, const float* __restrict__ gamma,
    const float* __restrict__ wqkv, const float* __restrict__ wproj,
    bf16* __restrict__ xn, bf16* __restrict__ wq, bf16* __restrict__ wp)
{
    const int tid = threadIdx.x;
    const int blk = blockIdx.x;
    if (blk >= 256) {
        // weight conversion, grid-stride over 589824 elems (128 blocks)
        int t0 = (blk - 256) * 256 + tid;
        for (int t = t0; t < 1152 * 384 + 384 * 384; t += 128 * 256) {
            if (t < 1152 * 384) wq[t] = (bf16)wqkv[t];
            else                wp[t - 1152 * 384] = (bf16)wproj[t - 1152 * 384];
        }
        return;
    }
    __shared__ float sG[384];
    __shared__ float sS[4][64];
    __shared__ float sScale[64];
    __shared__ bf16  sT[64][392];              // transpose tile, +8 elem pad
    const int w = tid >> 6, l = tid & 63;
    for (int i = tid; i < 384; i += 256) sG[i] = gamma[i];
    const int b = blk >> 6, p0 = (blk & 63) << 6;
    const float* xc = x + ((size_t)(b * 384 + 96 * w)) * 4096 + p0 + l;
    float v[96];
    float s0 = 0.f, s1 = 0.f;
#pragma unroll
    for (int c = 0; c < 96; c += 2) {
        v[c]     = xc[(size_t)c * 4096];
        v[c + 1] = xc[(size_t)(c + 1) * 4096];
        s0 += v[c] * v[c]; s1 += v[c + 1] * v[c + 1];
    }
    sS[w][l] = s0 + s1;
    __syncthreads();
    if (w == 0) {
        float t = (sS[0][l] + sS[1][l]) + (sS[2][l] + sS[3][l]);
        sScale[l] = 19.595917942265423f / fmaxf(sqrtf(t), 1e-12f); // sqrt(384)/max(l2,eps)
    }
    __syncthreads();
    float sc = sScale[l];
    // scale + convert into LDS transpose tile (row = token, cols 96w..96w+96)
#pragma unroll
    for (int c0 = 0; c0 < 96; c0 += 8) {
        bf16x8 v8;
#pragma unroll
        for (int j = 0; j < 8; ++j)
            v8[j] = (bf16)(v[c0 + j] * sc * sG[96 * w + c0 + j]);
        *(bf16x8*)(&sT[l][96 * w + c0]) = v8;
    }
    __syncthreads();
    // coalesced writeout: thread t -> row t>>2, segment t&3 (192B each)
    const int r = tid >> 2, seg = tid & 3;
    const bf16* srow = &sT[r][seg * 96];
    bf16* drow = xn + (size_t)((b << 12) + p0 + r) * 384 + seg * 96;
#pragma unroll
    for (int j = 0; j < 12; ++j)
        *(i32x4*)(drow + j * 8) = *(const i32x4*)(srow + j * 8);
}

// ---------------------------------------------------------------------------
// BT GEMM core: C[m][n] = sum_k A[m][k]*B[n][k], K=384 fixed, tile 128x128.
// mode 0: C fp8 = acc + bias_n[n], ldc given   (QK -> qkb)
// mode 1: C fp8 = acc + bias_m[m], ldc given   (V^T [d][16384] buffer)
// Epilogue routes the fp8 tile through LDS ([128][144] u8, reuses sA) so the
// global write is coalesced 64B/thread (was 1B scalar stores in 16B runs).
// ---------------------------------------------------------------------------
__device__ __forceinline__ void gemm_core_bt(
    bf16* sA, bf16* sB,
    const bf16* __restrict__ A, const bf16* __restrict__ B,
    const float* __restrict__ bias_m, const float* __restrict__ bias_n,
    uint8_t* __restrict__ Cout, const int mode, const int ldc,
    const int m0, const int n0)
{
    const int tid = threadIdx.x;
    const int l = tid & 63, w = tid >> 6;
    const int lo = l & 15, hi = l >> 4;
    const int wm = w >> 1, wn = w & 1;

    f32x4 acc[4][4] = {};

    for (int kt = 0; kt < 6; ++kt) {
        __syncthreads();
        const int k0 = kt * 64;
#pragma unroll
        for (int i = 0; i < 5; ++i) {
            int ci = i * 256 + tid;
            if (ci < 1152) {
                int row = ci / 9, off = ci % 9;  // off==8 loads harmless slack into pad
                gload16(A + (size_t)(m0 + row) * 384 + k0 + off * 8, (char*)sA + ci * 16);
                gload16(B + (size_t)(n0 + row) * 384 + k0 + off * 8, (char*)sB + ci * 16);
            }
        }
        __syncthreads();
#pragma unroll
        for (int ks = 0; ks < 2; ++ks) {
            bf16x8 af[4], bfr[4];
#pragma unroll
            for (int t = 0; t < 4; ++t)
                af[t] = *(const bf16x8*)(sA + (wm * 64 + t * 16 + lo) * 72 + ks * 32 + hi * 8);
#pragma unroll
            for (int t = 0; t < 4; ++t)
                bfr[t] = *(const bf16x8*)(sB + (wn * 64 + t * 16 + lo) * 72 + ks * 32 + hi * 8);
#pragma unroll
            for (int rt = 0; rt < 4; ++rt)
#pragma unroll
                for (int ct = 0; ct < 4; ++ct)
                    acc[rt][ct] = MFMA16(af[rt], bfr[ct], acc[rt][ct]);
        }
    }

    // epilogue: fp8 tile via LDS -> coalesced 64B/thread writes
    uint8_t* ctile = (uint8_t*)sA;             // [128][144] u8 = 18432B (sA region)
    __syncthreads();                           // all sA/sB compute reads done
#pragma unroll
    for (int rt = 0; rt < 4; ++rt) {
#pragma unroll
        for (int ct = 0; ct < 4; ++ct) {
            int row_l = wm * 64 + rt * 16 + hi * 4;
            int col_l = wn * 64 + ct * 16 + lo;
            if (mode == 0) {
                float bn = bias_n[n0 + col_l];
#pragma unroll
                for (int r = 0; r < 4; ++r)
                    ctile[(row_l + r) * 144 + col_l] = to_fp8(acc[rt][ct][r] + bn);
            } else {
#pragma unroll
                for (int r = 0; r < 4; ++r)
                    ctile[(row_l + r) * 144 + col_l] =
                        to_fp8(acc[rt][ct][r] + bias_m[m0 + row_l + r]);
            }
        }
    }
    __syncthreads();
    const int row = tid >> 1, hf = tid & 1;
    const uint8_t* srow = ctile + row * 144 + hf * 64;
    uint8_t* drow = Cout + (size_t)(m0 + row) * ldc + n0 + hf * 64;
#pragma unroll
    for (int j = 0; j < 4; ++j)
        *(i32x4*)(drow + j * 16) = *(const i32x4*)(srow + j * 16);
}

// Fused QKV: blocks [0,768) do QK (M=16384,N=768), [768,1152) do V^T (M=384,N=16384).
// XCD-grouped tile maps (wgid%8 = XCD): QK -> each XCD owns 16 m-tiles (A-panel
// 1.5MB L2-resident); V^T -> each XCD owns 16 n-tiles (B-panel 1.6MB).
__global__ __launch_bounds__(256) void gemm_qkv(
    const bf16* __restrict__ xn, const bf16* __restrict__ wq,
    const float* __restrict__ b_qkv, uint8_t* __restrict__ qkb,
    uint8_t* __restrict__ vtb)
{
    __shared__ bf16 sA[128 * 72];   // 144B rows (128B data + 16B pad)
    __shared__ bf16 sB[128 * 72];
    const int id = blockIdx.x;
    if (id < 768) {
        const int xcd = id & 7, s = id >> 3;       // s in [0,96)
        gemm_core_bt(sA, sB, xn, wq, nullptr, b_qkv, qkb, 0, 768,
                     (xcd * 16 + s / 6) * 128, (s % 6) * 128);
    } else {
        const int t = id - 768;                    // 768%8==0: t&7 == XCD
        const int xcd = t & 7, s = t >> 3;         // s in [0,48)
        gemm_core_bt(sA, sB, wq + (size_t)768 * 384, xn, b_qkv + 768, nullptr,
                     vtb, 1, 16384, (s % 3) * 128, (xcd * 16 + s / 3) * 128);
    }
}

// ---------------------------------------------------------------------------
// Proj GEMM with fused partial-merge: B rows are built on the fly as
// (a0*O0 + a1*O1)/(a0*l0 + a1*l1) from the two flash partials, then
// C = wp @ B^T + b_proj + resid, fp32 out in [b][c][h][w] layout.
// Epilogue: acc routed through an LDS f32 tile ([64][132], two 64-row
// passes, sA+sB merged buffer) -> 128B/thread contiguous writes, residual
// read with the same coalesced pattern, bias folded in.
// 1-D grid 384, XCD-grouped: each XCD owns 16 n-tiles (partials L2-resident).
// ---------------------------------------------------------------------------
__global__ __launch_bounds__(256) void gemm_proj(
    const bf16* __restrict__ wp, const bf16* __restrict__ p0,
    const bf16* __restrict__ p1, const float* __restrict__ ml,
    const float* __restrict__ b_proj, const float* __restrict__ x,
    float* __restrict__ out)
{
    __shared__ char gsm[36864];                // sA | sB, reused as f32 tile
    bf16* sA = (bf16*)gsm;
    bf16* sB = (bf16*)(gsm + 18432);
    const int tid = threadIdx.x;
    const int l = tid & 63, w = tid >> 6;
    const int lo = l & 15, hi = l >> 4;
    const int wm = w >> 1, wn = w & 1;
    const int id = blockIdx.x;
    const int xcd = id & 7, s = id >> 3;           // s in [0,48)
    const int m0 = (s % 3) * 128, n0 = (xcd * 16 + s / 3) * 128;

    f32x4 acc[4][4] = {};

    for (int kt = 0; kt < 6; ++kt) {
        __syncthreads();
        const int k0 = kt * 64;
#pragma unroll
        for (int i = 0; i < 5; ++i) {
            int ci = i * 256 + tid;
            if (ci < 1152) {
                int row = ci / 9, off = ci % 9;
                gload16(wp + (size_t)(m0 + row) * 384 + k0 + off * 8, (char*)sA + ci * 16);
                // merged B chunk
                int tok = n0 + row;
                float2 ml0 = *(const float2*)(ml + (size_t)tok * 2);
                float2 ml1 = *(const float2*)(ml + (size_t)(16384 + tok) * 2);
                float mM = fmaxf(ml0.x, ml1.x);
                float a0 = EXP2(ml0.x - mM), a1 = EXP2(ml1.x - mM);
                float inv = 1.0f / (a0 * ml0.y + a1 * ml1.y);
                float w0 = a0 * inv, w1 = a1 * inv;
                size_t boff = (size_t)tok * 384 + k0 + off * 8;  // off==8: slack into pad
                bf16x8 v0 = *(const bf16x8*)(p0 + boff);
                bf16x8 v1 = *(const bf16x8*)(p1 + boff);
                bf16x8 r;
#pragma unroll
                for (int j = 0; j < 8; ++j)
                    r[j] = (bf16)((float)v0[j] * w0 + (float)v1[j] * w1);
                *(bf16x8*)((char*)sB + ci * 16) = r;
            }
        }
        __syncthreads();
#pragma unroll
        for (int ks = 0; ks < 2; ++ks) {
            bf16x8 af[4], bfr[4];
#pragma unroll
            for (int t = 0; t < 4; ++t)
                af[t] = *(const bf16x8*)(sA + (wm * 64 + t * 16 + lo) * 72 + ks * 32 + hi * 8);
#pragma unroll
            for (int t = 0; t < 4; ++t)
                bfr[t] = *(const bf16x8*)(sB + (wn * 64 + t * 16 + lo) * 72 + ks * 32 + hi * 8);
#pragma unroll
            for (int rt = 0; rt < 4; ++rt)
#pragma unroll
                for (int ct = 0; ct < 4; ++ct)
                    acc[rt][ct] = MFMA16(af[rt], bfr[ct], acc[rt][ct]);
        }
    }

    // epilogue: coalesced via LDS f32 tile, 2 passes of 64 channel-rows
    float* tile = (float*)gsm;                 // [64][132] f32 = 33792B
    const int bb = n0 >> 12, pp0 = n0 & 4095;
    for (int pass = 0; pass < 2; ++pass) {
        __syncthreads();                       // prev reads / compute done
        if (wm == pass) {
#pragma unroll
            for (int rt = 0; rt < 4; ++rt)
#pragma unroll
                for (int ct = 0; ct < 4; ++ct) {
                    int row_l = rt * 16 + hi * 4;
                    int col_l = wn * 64 + ct * 16 + lo;
#pragma unroll
                    for (int r = 0; r < 4; ++r)
                        tile[(row_l + r) * 132 + col_l] = acc[rt][ct][r];
                }
        }
        __syncthreads();
        const int row = tid >> 2, qu = tid & 3;
        const int mch = m0 + pass * 64 + row;
        const float bp = b_proj[mch];
        const size_t gbase = ((size_t)(bb * 384 + mch)) * 4096 + pp0 + qu * 32;
        const float* trow = tile + row * 132 + qu * 32;
#pragma unroll
        for (int j = 0; j < 8; ++j) {
            f32x4 a4 = *(const f32x4*)(trow + j * 4);
            f32x4 x4 = *(const f32x4*)(x + gbase + j * 4);
#pragma unroll
            for (int k = 0; k < 4; ++k) a4[k] = a4[k] + bp + x4[k];
            *(f32x4*)(out + gbase + j * 4) = a4;
        }
    }
}

// ---------------------------------------------------------------------------
// Flash attention (R10 configuration -- best measured 106.5us): transposed-S,
// MX-fp8 32x32x64, Bk=64. LDS dynamic 81920B = 2 blocks/CU x 80KB = 160KB:
// K double-buffered 2x[64][400]=51200 + V^T single [384][80]=30720.
// Schedule/iter: {issue V[t]+K[t+1] DMA -> QK+softmax from K[c] -> barrier A
// -> PV from sV -> barrier B}. Hoisted staging offsets. Forward kv order for
// all blocks (R11 de-phase probe regressed; reverted).
// qk [16384][768] fp8 (Q|K), vt [384][16384] fp8 (V^T).
// Grid 512: bh = id&7 (one (b,half) per XCD, K/V set 1.5MB L2-resident).
// Online softmax with T13 defer-max (thr 8 in log2 dom; P<=2^8 < fp8 448).
// ---------------------------------------------------------------------------
__global__ __launch_bounds__(256, 2) void flash_kernel(
    const uint8_t* __restrict__ qk, const uint8_t* __restrict__ vt,
    bf16* __restrict__ op0, bf16* __restrict__ op1, float* __restrict__ ml)
{
    extern __shared__ char smem[];             // K bufs @0/25600, V @51200
    uint8_t* sbase = (uint8_t*)smem;
    uint8_t* sV = sbase + 51200;
    const int tid = threadIdx.x;
    const int l = tid & 63, w = tid >> 6;
    const int l31 = l & 31, hi2 = l >> 5;
    const int wq = w >> 1, wd = w & 1;
    const int id = blockIdx.x;
    const int qt = id >> 3, bh = id & 7;       // bh == wgid%8 -> one bh per XCD
    const int b = bh >> 1, half = bh & 1;
    const int q0 = b * 4096 + qt * 64;
    const int kvbase = b * 4096 + half * 2048;
    const float SC = 0.07362217057594547f;     // (1/sqrt(384)) * log2(e)
    const float THR = 108.664f;                // 8 / SC (defer-max threshold)

    // hoisted K staging offsets: 1600 chunks (64 rows x 25; 24 data + 1 pad)
    uint32_t ksrc[7];
#pragma unroll
    for (int i = 0; i < 7; ++i) {
        int ci = i * 256 + tid;
        int row = ci / 25, off = ci % 25;      // off==24 stages slack into pad
        ksrc[i] = (uint32_t)((kvbase + row) * 768 + 384 + off * 16);
    }
    // hoisted V staging offsets: 1920 chunks (384 rows x 5; 4 data + 1 pad)
    uint32_t vsrc[8];
#pragma unroll
    for (int i = 0; i < 8; ++i) {
        int ci = i * 256 + tid;
        int row = ci / 5, off = ci % 5;
        vsrc[i] = (uint32_t)(row * 16384 + kvbase + off * 16);
    }
    // prologue: K[0] into buf 0
#pragma unroll
    for (int i = 0; i < 7; ++i) {
        if (i < 6 || tid < 64) gload16(qk + ksrc[i], sbase + i * 4096 + tid * 16);
        ksrc[i] += 49152;                      // advance one kv-tile (64*768)
    }

    // Q B-frags: lane (l31=q, hi2) holds Q[q0+wq*32+l31][ksw*64 + hi2*32 + j]
    i32x8 qf[6];
    {
        const uint8_t* qrow = qk + (size_t)(q0 + wq * 32 + l31) * 768 + hi2 * 32;
#pragma unroll
        for (int ksw = 0; ksw < 6; ++ksw)
            qf[ksw] = ld32(qrow + ksw * 64);
    }

    f32x16 o[6] = {};    // o[dt]: q=l31, d = wd*192+dt*32+(r&3)+8*(r>>2)+4*hi2
    float m = -1e30f, lsum = 0.f;              // raw-score domain

    __syncthreads();                           // K[0] staged (drains vmcnt)

    int c = 0;                                 // current K buf: byte offset c*25600
    for (int kt = 0; kt < 32; ++kt) {
        // issue V[t] + K[t+1] staging; lands under QK+softmax compute
#pragma unroll
        for (int i = 0; i < 8; ++i) {
            if (i < 7 || tid < 128) gload16(vt + vsrc[i], sV + i * 4096 + tid * 16);
            vsrc[i] += 64;
        }
        if (kt < 31) {
            uint8_t* dst = sbase + (c ^ 1) * 25600;
#pragma unroll
            for (int i = 0; i < 7; ++i) {
                if (i < 6 || tid < 64) gload16(qk + ksrc[i], dst + i * 4096 + tid * 16);
                ksrc[i] += 49152;
            }
        }

        // S^T[64kv][32q] as two 32x32 tiles (kvt): A = K rows, B = Q regs
        const uint8_t* sK = sbase + c * 25600;
        f32x16 s0 = {}, s1 = {};
        __builtin_amdgcn_s_setprio(1);
#pragma unroll
        for (int ksw = 0; ksw < 6; ++ksw) {
            i32x8 ak0 = ld32(sK + (size_t)l31 * 400 + ksw * 64 + hi2 * 32);
            i32x8 ak1 = ld32(sK + (size_t)(32 + l31) * 400 + ksw * 64 + hi2 * 32);
            s0 = MFMA_MX(ak0, qf[ksw], s0);
            s1 = MFMA_MX(ak1, qf[ksw], s1);
        }
        __builtin_amdgcn_s_setprio(0);

        // online softmax: lane holds 32 kv (own hi2 blocks) for q=l31
        float a0 = fmaxf(fmaxf(s0[0],  s0[1]),  fmaxf(s0[2],  s0[3]));
        float a1 = fmaxf(fmaxf(s0[4],  s0[5]),  fmaxf(s0[6],  s0[7]));
        float a2 = fmaxf(fmaxf(s0[8],  s0[9]),  fmaxf(s0[10], s0[11]));
        float a3 = fmaxf(fmaxf(s0[12], s0[13]), fmaxf(s0[14], s0[15]));
        float b0 = fmaxf(fmaxf(s1[0],  s1[1]),  fmaxf(s1[2],  s1[3]));
        float b1 = fmaxf(fmaxf(s1[4],  s1[5]),  fmaxf(s1[6],  s1[7]));
        float b2 = fmaxf(fmaxf(s1[8],  s1[9]),  fmaxf(s1[10], s1[11]));
        float b3 = fmaxf(fmaxf(s1[12], s1[13]), fmaxf(s1[14], s1[15]));
        float mx = fmaxf(fmaxf(fmaxf(a0, a1), fmaxf(a2, a3)),
                         fmaxf(fmaxf(b0, b1), fmaxf(b2, b3)));
        mx = fmaxf(mx, __shfl_xor(mx, 32));
        if (__any(mx > m + THR)) {             // T13: rare (first iter + big jumps)
            float mn = fmaxf(m, mx);
            float alpha = EXP2((m - mn) * SC);
            m = mn;
            lsum *= alpha;
#pragma unroll
            for (int dt = 0; dt < 6; ++dt)
#pragma unroll
                for (int r = 0; r < 16; ++r) o[dt][r] *= alpha;
        }
        float p0[16], p1[16];
        float msc = m * SC;
        float rsa = 0.f, rsb = 0.f, rsc = 0.f, rsd = 0.f;
#pragma unroll
        for (int r = 0; r < 16; r += 4) {
            p0[r]     = EXP2(fmaf(s0[r],     SC, -msc)); rsa += p0[r];
            p0[r + 1] = EXP2(fmaf(s0[r + 1], SC, -msc)); rsb += p0[r + 1];
            p0[r + 2] = EXP2(fmaf(s0[r + 2], SC, -msc)); rsc += p0[r + 2];
            p0[r + 3] = EXP2(fmaf(s0[r + 3], SC, -msc)); rsd += p0[r + 3];
        }
#pragma unroll
        for (int r = 0; r < 16; r += 4) {
            p1[r]     = EXP2(fmaf(s1[r],     SC, -msc)); rsa += p1[r];
            p1[r + 1] = EXP2(fmaf(s1[r + 1], SC, -msc)); rsb += p1[r + 1];
            p1[r + 2] = EXP2(fmaf(s1[r + 2], SC, -msc)); rsc += p1[r + 2];
            p1[r + 3] = EXP2(fmaf(s1[r + 3], SC, -msc)); rsd += p1[r + 3];
        }
        float rs = (rsa + rsb) + (rsc + rsd);
        rs += __shfl_xor(rs, 32);
        lsum += rs;

        // pack P to fp8 dwords. s-reg r of kvt holds kv = kvt*32+(r&3)+8*(r>>2)+4*hi2.
        // own pk dword i = kv {kvt*32 + 8i + 4*hi2 .. +3}. B-frag (this lane) needs
        // kv {hi2*32 + j}: kvt = hi2, interleave own/partner(xor32) dwords.
        int pk0[4], pk1[4];
#pragma unroll
        for (int i = 0; i < 4; ++i) {
            int d = __builtin_amdgcn_cvt_pk_fp8_f32(p0[4 * i], p0[4 * i + 1], 0, false);
            pk0[i] = __builtin_amdgcn_cvt_pk_fp8_f32(p0[4 * i + 2], p0[4 * i + 3], d, true);
            d = __builtin_amdgcn_cvt_pk_fp8_f32(p1[4 * i], p1[4 * i + 1], 0, false);
            pk1[i] = __builtin_amdgcn_cvt_pk_fp8_f32(p1[4 * i + 2], p1[4 * i + 3], d, true);
        }
        i32x8 pf;
#pragma unroll
        for (int i = 0; i < 4; ++i) {
            int x0 = __shfl_xor(pk0[i], 32);   // partner's kvt=0 dword
            int x1 = __shfl_xor(pk1[i], 32);   // partner's kvt=1 dword
            int own = hi2 ? pk1[i] : pk0[i];
            int oth = hi2 ? x1 : x0;
            pf[2 * i]     = hi2 ? oth : own;   // kv 8i+0..3 (rel. to hi2*32)
            pf[2 * i + 1] = hi2 ? own : oth;   // kv 8i+4..7
        }

        __syncthreads();                       // A: V[t] (+K[t+1]) landed everywhere

        // O^T[d][q] += V^T · P^T  (A: V^T rows m=d, k = kv = hi2*32+j, K=64)
        __builtin_amdgcn_s_setprio(1);
#pragma unroll
        for (int dt = 0; dt < 6; ++dt) {
            i32x8 av = ld32(sV + (size_t)(wd * 192 + dt * 32 + l31) * 80 + hi2 * 32);
            o[dt] = MFMA_MX(av, pf, o[dt]);
        }
        __builtin_amdgcn_s_setprio(0);

        __syncthreads();                       // B: sV reads done before next overwrite
        c ^= 1;
    }

    // epilogue: per-wave O^T -> O transpose through LDS (disjoint 4608B/wave)
    float* tr = (float*)(smem + w * 4608);     // [32 q][36 pitch] fp32
    bf16* dst = half ? op1 : op0;
#pragma unroll
    for (int dt = 0; dt < 6; ++dt) {
#pragma unroll
        for (int r = 0; r < 16; ++r) {
            int d32 = (r & 3) + 8 * (r >> 2) + 4 * hi2;
            tr[l31 * 36 + d32] = o[dt][r];
        }
        f32x4 v0 = *(f32x4*)(tr + l31 * 36 + hi2 * 16 + 0);
        f32x4 v1 = *(f32x4*)(tr + l31 * 36 + hi2 * 16 + 4);
        f32x4 v2 = *(f32x4*)(tr + l31 * 36 + hi2 * 16 + 8);
        f32x4 v3 = *(f32x4*)(tr + l31 * 36 + hi2 * 16 + 12);
        bf16x8 h0, h1;
#pragma unroll
        for (int j = 0; j < 4; ++j) {
            h0[j] = (bf16)v0[j]; h0[4 + j] = (bf16)v1[j];
            h1[j] = (bf16)v2[j]; h1[4 + j] = (bf16)v3[j];
        }
        size_t tok = (size_t)(q0 + wq * 32 + l31);
        bf16* drow = dst + tok * 384 + wd * 192 + dt * 32 + hi2 * 16;
        *(bf16x8*)(drow + 0) = h0;
        *(bf16x8*)(drow + 8) = h1;
    }
    if (wd == 0 && hi2 == 0) {
        int tok = q0 + wq * 32 + l31;
        ml[(size_t)(half * 16384 + tok) * 2 + 0] = m * SC;   // scaled domain
        ml[(size_t)(half * 16384 + tok) * 2 + 1] = lsum;
    }
}

// ---------------------------------------------------------------------------
extern "C" void kernel_launch(void* const* d_in, const int* in_sizes, int n_in,
                              void* d_out, int out_size, void* d_ws, size_t ws_size,
                              hipStream_t stream) {
    const float* x      = (const float*)d_in[0];
    const float* gamma  = (const float*)d_in[1];
    const float* w_qkv  = (const float*)d_in[2];
    const float* b_qkv  = (const float*)d_in[3];
    const float* w_proj = (const float*)d_in[4];
    const float* b_proj = (const float*)d_in[5];
    float* out = (float*)d_out;

    // workspace carve (~46 MiB); staging 16B overreads at buffer tails land
    // in the next ws buffer. xn is dead after the qkv gemm -> reused as op0.
    char* ws = (char*)d_ws;
    bf16* xn  = (bf16*)ws;    ws += (size_t)16384 * 384 * 2;   // normalized x / flash partial-0
    uint8_t* qkb = (uint8_t*)ws; ws += (size_t)16384 * 768;    // Q|K fp8, [tok][768]
    uint8_t* vtb = (uint8_t*)ws; ws += (size_t)384 * 16384;    // V^T fp8, [d][tok]
    bf16* ob  = (bf16*)ws;    ws += (size_t)16384 * 384 * 2;   // flash partial-1
    bf16* wqb = (bf16*)ws;    ws += (size_t)1152 * 384 * 2;    // w_qkv bf16
    bf16* wpb = (bf16*)ws;    ws += (size_t)384 * 384 * 2;     // w_proj bf16
    float* mlb = (float*)ws;  ws += (size_t)2 * 16384 * 2 * 4; // m*SC,l per (half, tok)

    // dynamic LDS for flash: 81920B (2 blocks/CU x 80KB = 160KB exactly)
    (void)hipFuncSetAttribute((const void*)flash_kernel,
                              hipFuncAttributeMaxDynamicSharedMemorySize, 81920);

    // norm (blocks 0..255, LDS-transposed coalesced writes) + convert (256..383)
    norm_kernel<<<384, 256, 0, stream>>>(x, gamma, w_qkv, w_proj, xn, wqb, wpb);
    // fused QK fp8 [tok][768] + V^T fp8 [d][tok] (coalesced LDS epilogues)
    gemm_qkv<<<1152, 256, 0, stream>>>(xn, wqb, b_qkv, qkb, vtb);
    flash_kernel<<<512, 256, 81920, stream>>>(qkb, vtb, xn, ob, mlb);
    // proj + fused partial-merge + bias + residual (coalesced LDS epilogue)
    gemm_proj<<<384, 256, 0, stream>>>(wpb, xn, ob, mlb, b_proj, x, out);
}

// Round 13
// 236.937 us; speedup vs baseline: 1.0251x; 1.0251x over previous
//
#include <hip/hip_runtime.h>
#include <cstdint>
#include <cstddef>

typedef __bf16 bf16;
typedef __bf16 bf16x8 __attribute__((ext_vector_type(8)));
typedef float  f32x4 __attribute__((ext_vector_type(4)));
typedef float  f32x16 __attribute__((ext_vector_type(16)));
typedef int    i32x4 __attribute__((ext_vector_type(4)));
typedef int    i32x8 __attribute__((ext_vector_type(8)));

#define MFMA16(a, b, c) __builtin_amdgcn_mfma_f32_16x16x32_bf16((a), (b), (c), 0, 0, 0)
// MX-scaled fp8 MFMA, both scales = 1.0 (E8M0 127): fmt a=b=0 (fp8 e4m3)
#define MFMA_MX(a, b, c) \
    __builtin_amdgcn_mfma_scale_f32_32x32x64_f8f6f4((a), (b), (c), 0, 0, 0, 0x7F, 0, 0x7F)

#if __has_builtin(__builtin_amdgcn_exp2f)
#define EXP2(x) __builtin_amdgcn_exp2f(x)
#else
#define EXP2(x) exp2f(x)
#endif

// float -> fp8 e4m3 (OCP), RNE, single byte
__device__ __forceinline__ uint8_t to_fp8(float v) {
    return (uint8_t)(__builtin_amdgcn_cvt_pk_fp8_f32(v, v, 0, false) & 0xff);
}

// 32B load as two 16B vector loads (LDS: 2x ds_read_b128; global: 2x dwordx4)
__device__ __forceinline__ i32x8 ld32(const void* p) {
    i32x4 a = *(const i32x4*)p;
    i32x4 b = *(const i32x4*)((const char*)p + 16);
    i32x8 r;
    r[0] = a[0]; r[1] = a[1]; r[2] = a[2]; r[3] = a[3];
    r[4] = b[0]; r[5] = b[1]; r[6] = b[2]; r[7] = b[3];
    return r;
}

// async global->LDS, 16B per lane. LDS dest is wave-uniform base + lane*16.
__device__ __forceinline__ void gload16(const void* g, void* l) {
    __builtin_amdgcn_global_load_lds(
        (const __attribute__((address_space(1))) unsigned int*)g,
        (__attribute__((address_space(3))) unsigned int*)l,
        16, 0, 0);
}

// ---------------------------------------------------------------------------
// RMSNorm + (blocks 256..383) weight fp32->bf16 conversion.
// Blocks 0..255: 64 tokens each; wave w owns channel quarter [96w,96w+96),
// lane l owns token p0+l; values live in registers. Output goes through an
// LDS [64][392] transpose tile so the xn write is fully coalesced.
// x [4][384][4096] fp32 -> xn [16384][384] bf16.
// ---------------------------------------------------------------------------
__global__ __launch_bounds__(256) void norm_kernel(
    const float* __restrict__ x, const float* __restrict__ gamma,
    const float* __restrict__ wqkv, const float* __restrict__ wproj,
    bf16* __restrict__ xn, bf16* __restrict__ wq, bf16* __restrict__ wp)
{
    const int tid = threadIdx.x;
    const int blk = blockIdx.x;
    if (blk >= 256) {
        // weight conversion, grid-stride over 589824 elems (128 blocks)
        int t0 = (blk - 256) * 256 + tid;
        for (int t = t0; t < 1152 * 384 + 384 * 384; t += 128 * 256) {
            if (t < 1152 * 384) wq[t] = (bf16)wqkv[t];
            else                wp[t - 1152 * 384] = (bf16)wproj[t - 1152 * 384];
        }
        return;
    }
    __shared__ float sG[384];
    __shared__ float sS[4][64];
    __shared__ float sScale[64];
    __shared__ bf16  sT[64][392];              // transpose tile, +8 elem pad
    const int w = tid >> 6, l = tid & 63;
    for (int i = tid; i < 384; i += 256) sG[i] = gamma[i];
    const int b = blk >> 6, p0 = (blk & 63) << 6;
    const float* xc = x + ((size_t)(b * 384 + 96 * w)) * 4096 + p0 + l;
    float v[96];
    float s0 = 0.f, s1 = 0.f;
#pragma unroll
    for (int c = 0; c < 96; c += 2) {
        v[c]     = xc[(size_t)c * 4096];
        v[c + 1] = xc[(size_t)(c + 1) * 4096];
        s0 += v[c] * v[c]; s1 += v[c + 1] * v[c + 1];
    }
    sS[w][l] = s0 + s1;
    __syncthreads();
    if (w == 0) {
        float t = (sS[0][l] + sS[1][l]) + (sS[2][l] + sS[3][l]);
        sScale[l] = 19.595917942265423f / fmaxf(sqrtf(t), 1e-12f); // sqrt(384)/max(l2,eps)
    }
    __syncthreads();
    float sc = sScale[l];
    // scale + convert into LDS transpose tile (row = token, cols 96w..96w+96)
#pragma unroll
    for (int c0 = 0; c0 < 96; c0 += 8) {
        bf16x8 v8;
#pragma unroll
        for (int j = 0; j < 8; ++j)
            v8[j] = (bf16)(v[c0 + j] * sc * sG[96 * w + c0 + j]);
        *(bf16x8*)(&sT[l][96 * w + c0]) = v8;
    }
    __syncthreads();
    // coalesced writeout: thread t -> row t>>2, segment t&3 (192B each)
    const int r = tid >> 2, seg = tid & 3;
    const bf16* srow = &sT[r][seg * 96];
    bf16* drow = xn + (size_t)((b << 12) + p0 + r) * 384 + seg * 96;
#pragma unroll
    for (int j = 0; j < 12; ++j)
        *(i32x4*)(drow + j * 8) = *(const i32x4*)(srow + j * 8);
}

// ---------------------------------------------------------------------------
// BT GEMM core: C[m][n] = sum_k A[m][k]*B[n][k], K=384 fixed, tile 128x128.
// mode 0: C fp8 = acc + bias_n[n], ldc given   (QK -> qkb)
// mode 1: C fp8 = acc + bias_m[m], ldc given   (V^T [d][16384] buffer)
// Direct scalar fp8 stores (R12's LDS-epilogue variant regressed ~10us:
// stores were already 64B-runs-per-quad; extra barriers cost more).
// ---------------------------------------------------------------------------
__device__ __forceinline__ void gemm_core_bt(
    bf16* sA, bf16* sB,
    const bf16* __restrict__ A, const bf16* __restrict__ B,
    const float* __restrict__ bias_m, const float* __restrict__ bias_n,
    uint8_t* __restrict__ Cout, const int mode, const int ldc,
    const int m0, const int n0)
{
    const int tid = threadIdx.x;
    const int l = tid & 63, w = tid >> 6;
    const int lo = l & 15, hi = l >> 4;
    const int wm = w >> 1, wn = w & 1;

    f32x4 acc[4][4] = {};

    for (int kt = 0; kt < 6; ++kt) {
        __syncthreads();
        const int k0 = kt * 64;
#pragma unroll
        for (int i = 0; i < 5; ++i) {
            int ci = i * 256 + tid;
            if (ci < 1152) {
                int row = ci / 9, off = ci % 9;  // off==8 loads harmless slack into pad
                gload16(A + (size_t)(m0 + row) * 384 + k0 + off * 8, (char*)sA + ci * 16);
                gload16(B + (size_t)(n0 + row) * 384 + k0 + off * 8, (char*)sB + ci * 16);
            }
        }
        __syncthreads();
#pragma unroll
        for (int ks = 0; ks < 2; ++ks) {
            bf16x8 af[4], bfr[4];
#pragma unroll
            for (int t = 0; t < 4; ++t)
                af[t] = *(const bf16x8*)(sA + (wm * 64 + t * 16 + lo) * 72 + ks * 32 + hi * 8);
#pragma unroll
            for (int t = 0; t < 4; ++t)
                bfr[t] = *(const bf16x8*)(sB + (wn * 64 + t * 16 + lo) * 72 + ks * 32 + hi * 8);
#pragma unroll
            for (int rt = 0; rt < 4; ++rt)
#pragma unroll
                for (int ct = 0; ct < 4; ++ct)
                    acc[rt][ct] = MFMA16(af[rt], bfr[ct], acc[rt][ct]);
        }
    }

    // epilogue: C/D layout col = lo, row = hi*4 + reg
#pragma unroll
    for (int rt = 0; rt < 4; ++rt) {
#pragma unroll
        for (int ct = 0; ct < 4; ++ct) {
            int mb = m0 + wm * 64 + rt * 16 + hi * 4;
            int n  = n0 + wn * 64 + ct * 16 + lo;
            if (mode == 0) {
                float bn = bias_n[n];
#pragma unroll
                for (int r = 0; r < 4; ++r)
                    Cout[(size_t)(mb + r) * ldc + n] = to_fp8(acc[rt][ct][r] + bn);
            } else {
#pragma unroll
                for (int r = 0; r < 4; ++r)
                    Cout[(size_t)(mb + r) * ldc + n] = to_fp8(acc[rt][ct][r] + bias_m[mb + r]);
            }
        }
    }
}

// Fused QKV: blocks [0,768) do QK (M=16384,N=768), [768,1152) do V^T (M=384,N=16384).
// XCD-grouped tile maps (wgid%8 = XCD): QK -> each XCD owns 16 m-tiles (A-panel
// 1.5MB L2-resident); V^T -> each XCD owns 16 n-tiles (B-panel 1.6MB).
__global__ __launch_bounds__(256) void gemm_qkv(
    const bf16* __restrict__ xn, const bf16* __restrict__ wq,
    const float* __restrict__ b_qkv, uint8_t* __restrict__ qkb,
    uint8_t* __restrict__ vtb)
{
    __shared__ bf16 sA[128 * 72];   // 144B rows (128B data + 16B pad)
    __shared__ bf16 sB[128 * 72];
    const int id = blockIdx.x;
    if (id < 768) {
        const int xcd = id & 7, s = id >> 3;       // s in [0,96)
        gemm_core_bt(sA, sB, xn, wq, nullptr, b_qkv, qkb, 0, 768,
                     (xcd * 16 + s / 6) * 128, (s % 6) * 128);
    } else {
        const int t = id - 768;                    // 768%8==0: t&7 == XCD
        const int xcd = t & 7, s = t >> 3;         // s in [0,48)
        gemm_core_bt(sA, sB, wq + (size_t)768 * 384, xn, b_qkv + 768, nullptr,
                     vtb, 1, 16384, (s % 3) * 128, (xcd * 16 + s / 3) * 128);
    }
}

// ---------------------------------------------------------------------------
// Proj GEMM with fused partial-merge: B rows are built on the fly as
// (a0*O0 + a1*O1)/(a0*l0 + a1*l1) from the two flash partials, then
// C = wp @ B^T + b_proj + resid, fp32 out in [b][c][h][w] layout.
// Direct stores (R12's LDS-epilogue variant regressed; reverted).
// 1-D grid 384, XCD-grouped: each XCD owns 16 n-tiles (partials L2-resident).
// ---------------------------------------------------------------------------
__global__ __launch_bounds__(256) void gemm_proj(
    const bf16* __restrict__ wp, const bf16* __restrict__ p0,
    const bf16* __restrict__ p1, const float* __restrict__ ml,
    const float* __restrict__ b_proj, const float* __restrict__ x,
    float* __restrict__ out)
{
    __shared__ bf16 sA[128 * 72];
    __shared__ bf16 sB[128 * 72];
    const int tid = threadIdx.x;
    const int l = tid & 63, w = tid >> 6;
    const int lo = l & 15, hi = l >> 4;
    const int wm = w >> 1, wn = w & 1;
    const int id = blockIdx.x;
    const int xcd = id & 7, s = id >> 3;           // s in [0,48)
    const int m0 = (s % 3) * 128, n0 = (xcd * 16 + s / 3) * 128;

    f32x4 acc[4][4] = {};

    for (int kt = 0; kt < 6; ++kt) {
        __syncthreads();
        const int k0 = kt * 64;
#pragma unroll
        for (int i = 0; i < 5; ++i) {
            int ci = i * 256 + tid;
            if (ci < 1152) {
                int row = ci / 9, off = ci % 9;
                gload16(wp + (size_t)(m0 + row) * 384 + k0 + off * 8, (char*)sA + ci * 16);
                // merged B chunk
                int tok = n0 + row;
                float2 ml0 = *(const float2*)(ml + (size_t)tok * 2);
                float2 ml1 = *(const float2*)(ml + (size_t)(16384 + tok) * 2);
                float mM = fmaxf(ml0.x, ml1.x);
                float a0 = EXP2(ml0.x - mM), a1 = EXP2(ml1.x - mM);
                float inv = 1.0f / (a0 * ml0.y + a1 * ml1.y);
                float w0 = a0 * inv, w1 = a1 * inv;
                size_t boff = (size_t)tok * 384 + k0 + off * 8;  // off==8: slack into pad
                bf16x8 v0 = *(const bf16x8*)(p0 + boff);
                bf16x8 v1 = *(const bf16x8*)(p1 + boff);
                bf16x8 r;
#pragma unroll
                for (int j = 0; j < 8; ++j)
                    r[j] = (bf16)((float)v0[j] * w0 + (float)v1[j] * w1);
                *(bf16x8*)((char*)sB + ci * 16) = r;
            }
        }
        __syncthreads();
#pragma unroll
        for (int ks = 0; ks < 2; ++ks) {
            bf16x8 af[4], bfr[4];
#pragma unroll
            for (int t = 0; t < 4; ++t)
                af[t] = *(const bf16x8*)(sA + (wm * 64 + t * 16 + lo) * 72 + ks * 32 + hi * 8);
#pragma unroll
            for (int t = 0; t < 4; ++t)
                bfr[t] = *(const bf16x8*)(sB + (wn * 64 + t * 16 + lo) * 72 + ks * 32 + hi * 8);
#pragma unroll
            for (int rt = 0; rt < 4; ++rt)
#pragma unroll
                for (int ct = 0; ct < 4; ++ct)
                    acc[rt][ct] = MFMA16(af[rt], bfr[ct], acc[rt][ct]);
        }
    }

#pragma unroll
    for (int rt = 0; rt < 4; ++rt) {
#pragma unroll
        for (int ct = 0; ct < 4; ++ct) {
            int mb = m0 + wm * 64 + rt * 16 + hi * 4;
            int n  = n0 + wn * 64 + ct * 16 + lo;
            int bb = n >> 12, p = n & 4095;
#pragma unroll
            for (int r = 0; r < 4; ++r) {
                int m = mb + r;
                size_t idx = ((size_t)(bb * 384 + m)) * 4096 + p;
                out[idx] = acc[rt][ct][r] + b_proj[m] + x[idx];
            }
        }
    }
}

// ---------------------------------------------------------------------------
// Flash attention (best measured config, 106.5-109us): transposed-S,
// MX-fp8 32x32x64, Bk=64. LDS dynamic 81920B = 2 blocks/CU x 80KB = 160KB:
// K double-buffered 2x[64][400]=51200 + V^T single [384][80]=30720.
// Schedule/iter: {issue V[t]+K[t+1] DMA -> QK+softmax from K[c] -> barrier A
// -> PV from sV -> barrier B}. Hoisted staging offsets. Forward kv order.
// qk [16384][768] fp8 (Q|K), vt [384][16384] fp8 (V^T).
// Grid 512: bh = id&7 (one (b,half) per XCD, K/V set 1.5MB L2-resident).
// Online softmax with T13 defer-max (thr 8 in log2 dom; P<=2^8 < fp8 448).
// ---------------------------------------------------------------------------
__global__ __launch_bounds__(256, 2) void flash_kernel(
    const uint8_t* __restrict__ qk, const uint8_t* __restrict__ vt,
    bf16* __restrict__ op0, bf16* __restrict__ op1, float* __restrict__ ml)
{
    extern __shared__ char smem[];             // K bufs @0/25600, V @51200
    uint8_t* sbase = (uint8_t*)smem;
    uint8_t* sV = sbase + 51200;
    const int tid = threadIdx.x;
    const int l = tid & 63, w = tid >> 6;
    const int l31 = l & 31, hi2 = l >> 5;
    const int wq = w >> 1, wd = w & 1;
    const int id = blockIdx.x;
    const int qt = id >> 3, bh = id & 7;       // bh == wgid%8 -> one bh per XCD
    const int b = bh >> 1, half = bh & 1;
    const int q0 = b * 4096 + qt * 64;
    const int kvbase = b * 4096 + half * 2048;
    const float SC = 0.07362217057594547f;     // (1/sqrt(384)) * log2(e)
    const float THR = 108.664f;                // 8 / SC (defer-max threshold)

    // hoisted K staging offsets: 1600 chunks (64 rows x 25; 24 data + 1 pad)
    uint32_t ksrc[7];
#pragma unroll
    for (int i = 0; i < 7; ++i) {
        int ci = i * 256 + tid;
        int row = ci / 25, off = ci % 25;      // off==24 stages slack into pad
        ksrc[i] = (uint32_t)((kvbase + row) * 768 + 384 + off * 16);
    }
    // hoisted V staging offsets: 1920 chunks (384 rows x 5; 4 data + 1 pad)
    uint32_t vsrc[8];
#pragma unroll
    for (int i = 0; i < 8; ++i) {
        int ci = i * 256 + tid;
        int row = ci / 5, off = ci % 5;
        vsrc[i] = (uint32_t)(row * 16384 + kvbase + off * 16);
    }
    // prologue: K[0] into buf 0
#pragma unroll
    for (int i = 0; i < 7; ++i) {
        if (i < 6 || tid < 64) gload16(qk + ksrc[i], sbase + i * 4096 + tid * 16);
        ksrc[i] += 49152;                      // advance one kv-tile (64*768)
    }

    // Q B-frags: lane (l31=q, hi2) holds Q[q0+wq*32+l31][ksw*64 + hi2*32 + j]
    i32x8 qf[6];
    {
        const uint8_t* qrow = qk + (size_t)(q0 + wq * 32 + l31) * 768 + hi2 * 32;
#pragma unroll
        for (int ksw = 0; ksw < 6; ++ksw)
            qf[ksw] = ld32(qrow + ksw * 64);
    }

    f32x16 o[6] = {};    // o[dt]: q=l31, d = wd*192+dt*32+(r&3)+8*(r>>2)+4*hi2
    float m = -1e30f, lsum = 0.f;              // raw-score domain

    __syncthreads();                           // K[0] staged (drains vmcnt)

    int c = 0;                                 // current K buf: byte offset c*25600
    for (int kt = 0; kt < 32; ++kt) {
        // issue V[t] + K[t+1] staging; lands under QK+softmax compute
#pragma unroll
        for (int i = 0; i < 8; ++i) {
            if (i < 7 || tid < 128) gload16(vt + vsrc[i], sV + i * 4096 + tid * 16);
            vsrc[i] += 64;
        }
        if (kt < 31) {
            uint8_t* dst = sbase + (c ^ 1) * 25600;
#pragma unroll
            for (int i = 0; i < 7; ++i) {
                if (i < 6 || tid < 64) gload16(qk + ksrc[i], dst + i * 4096 + tid * 16);
                ksrc[i] += 49152;
            }
        }

        // S^T[64kv][32q] as two 32x32 tiles (kvt): A = K rows, B = Q regs
        const uint8_t* sK = sbase + c * 25600;
        f32x16 s0 = {}, s1 = {};
        __builtin_amdgcn_s_setprio(1);
#pragma unroll
        for (int ksw = 0; ksw < 6; ++ksw) {
            i32x8 ak0 = ld32(sK + (size_t)l31 * 400 + ksw * 64 + hi2 * 32);
            i32x8 ak1 = ld32(sK + (size_t)(32 + l31) * 400 + ksw * 64 + hi2 * 32);
            s0 = MFMA_MX(ak0, qf[ksw], s0);
            s1 = MFMA_MX(ak1, qf[ksw], s1);
        }
        __builtin_amdgcn_s_setprio(0);

        // online softmax: lane holds 32 kv (own hi2 blocks) for q=l31
        float a0 = fmaxf(fmaxf(s0[0],  s0[1]),  fmaxf(s0[2],  s0[3]));
        float a1 = fmaxf(fmaxf(s0[4],  s0[5]),  fmaxf(s0[6],  s0[7]));
        float a2 = fmaxf(fmaxf(s0[8],  s0[9]),  fmaxf(s0[10], s0[11]));
        float a3 = fmaxf(fmaxf(s0[12], s0[13]), fmaxf(s0[14], s0[15]));
        float b0 = fmaxf(fmaxf(s1[0],  s1[1]),  fmaxf(s1[2],  s1[3]));
        float b1 = fmaxf(fmaxf(s1[4],  s1[5]),  fmaxf(s1[6],  s1[7]));
        float b2 = fmaxf(fmaxf(s1[8],  s1[9]),  fmaxf(s1[10], s1[11]));
        float b3 = fmaxf(fmaxf(s1[12], s1[13]), fmaxf(s1[14], s1[15]));
        float mx = fmaxf(fmaxf(fmaxf(a0, a1), fmaxf(a2, a3)),
                         fmaxf(fmaxf(b0, b1), fmaxf(b2, b3)));
        mx = fmaxf(mx, __shfl_xor(mx, 32));
        if (__any(mx > m + THR)) {             // T13: rare (first iter + big jumps)
            float mn = fmaxf(m, mx);
            float alpha = EXP2((m - mn) * SC);
            m = mn;
            lsum *= alpha;
#pragma unroll
            for (int dt = 0; dt < 6; ++dt)
#pragma unroll
                for (int r = 0; r < 16; ++r) o[dt][r] *= alpha;
        }
        float p0[16], p1[16];
        float msc = m * SC;
        float rsa = 0.f, rsb = 0.f, rsc = 0.f, rsd = 0.f;
#pragma unroll
        for (int r = 0; r < 16; r += 4) {
            p0[r]     = EXP2(fmaf(s0[r],     SC, -msc)); rsa += p0[r];
            p0[r + 1] = EXP2(fmaf(s0[r + 1], SC, -msc)); rsb += p0[r + 1];
            p0[r + 2] = EXP2(fmaf(s0[r + 2], SC, -msc)); rsc += p0[r + 2];
            p0[r + 3] = EXP2(fmaf(s0[r + 3], SC, -msc)); rsd += p0[r + 3];
        }
#pragma unroll
        for (int r = 0; r < 16; r += 4) {
            p1[r]     = EXP2(fmaf(s1[r],     SC, -msc)); rsa += p1[r];
            p1[r + 1] = EXP2(fmaf(s1[r + 1], SC, -msc)); rsb += p1[r + 1];
            p1[r + 2] = EXP2(fmaf(s1[r + 2], SC, -msc)); rsc += p1[r + 2];
            p1[r + 3] = EXP2(fmaf(s1[r + 3], SC, -msc)); rsd += p1[r + 3];
        }
        float rs = (rsa + rsb) + (rsc + rsd);
        rs += __shfl_xor(rs, 32);
        lsum += rs;

        // pack P to fp8 dwords. s-reg r of kvt holds kv = kvt*32+(r&3)+8*(r>>2)+4*hi2.
        // own pk dword i = kv {kvt*32 + 8i + 4*hi2 .. +3}. B-frag (this lane) needs
        // kv {hi2*32 + j}: kvt = hi2, interleave own/partner(xor32) dwords.
        int pk0[4], pk1[4];
#pragma unroll
        for (int i = 0; i < 4; ++i) {
            int d = __builtin_amdgcn_cvt_pk_fp8_f32(p0[4 * i], p0[4 * i + 1], 0, false);
            pk0[i] = __builtin_amdgcn_cvt_pk_fp8_f32(p0[4 * i + 2], p0[4 * i + 3], d, true);
            d = __builtin_amdgcn_cvt_pk_fp8_f32(p1[4 * i], p1[4 * i + 1], 0, false);
            pk1[i] = __builtin_amdgcn_cvt_pk_fp8_f32(p1[4 * i + 2], p1[4 * i + 3], d, true);
        }
        i32x8 pf;
#pragma unroll
        for (int i = 0; i < 4; ++i) {
            int x0 = __shfl_xor(pk0[i], 32);   // partner's kvt=0 dword
            int x1 = __shfl_xor(pk1[i], 32);   // partner's kvt=1 dword
            int own = hi2 ? pk1[i] : pk0[i];
            int oth = hi2 ? x1 : x0;
            pf[2 * i]     = hi2 ? oth : own;   // kv 8i+0..3 (rel. to hi2*32)
            pf[2 * i + 1] = hi2 ? own : oth;   // kv 8i+4..7
        }

        __syncthreads();                       // A: V[t] (+K[t+1]) landed everywhere

        // O^T[d][q] += V^T · P^T  (A: V^T rows m=d, k = kv = hi2*32+j, K=64)
        __builtin_amdgcn_s_setprio(1);
#pragma unroll
        for (int dt = 0; dt < 6; ++dt) {
            i32x8 av = ld32(sV + (size_t)(wd * 192 + dt * 32 + l31) * 80 + hi2 * 32);
            o[dt] = MFMA_MX(av, pf, o[dt]);
        }
        __builtin_amdgcn_s_setprio(0);

        __syncthreads();                       // B: sV reads done before next overwrite
        c ^= 1;
    }

    // epilogue: per-wave O^T -> O transpose through LDS (disjoint 4608B/wave)
    float* tr = (float*)(smem + w * 4608);     // [32 q][36 pitch] fp32
    bf16* dst = half ? op1 : op0;
#pragma unroll
    for (int dt = 0; dt < 6; ++dt) {
#pragma unroll
        for (int r = 0; r < 16; ++r) {
            int d32 = (r & 3) + 8 * (r >> 2) + 4 * hi2;
            tr[l31 * 36 + d32] = o[dt][r];
        }
        f32x4 v0 = *(f32x4*)(tr + l31 * 36 + hi2 * 16 + 0);
        f32x4 v1 = *(f32x4*)(tr + l31 * 36 + hi2 * 16 + 4);
        f32x4 v2 = *(f32x4*)(tr + l31 * 36 + hi2 * 16 + 8);
        f32x4 v3 = *(f32x4*)(tr + l31 * 36 + hi2 * 16 + 12);
        bf16x8 h0, h1;
#pragma unroll
        for (int j = 0; j < 4; ++j) {
            h0[j] = (bf16)v0[j]; h0[4 + j] = (bf16)v1[j];
            h1[j] = (bf16)v2[j]; h1[4 + j] = (bf16)v3[j];
        }
        size_t tok = (size_t)(q0 + wq * 32 + l31);
        bf16* drow = dst + tok * 384 + wd * 192 + dt * 32 + hi2 * 16;
        *(bf16x8*)(drow + 0) = h0;
        *(bf16x8*)(drow + 8) = h1;
    }
    if (wd == 0 && hi2 == 0) {
        int tok = q0 + wq * 32 + l31;
        ml[(size_t)(half * 16384 + tok) * 2 + 0] = m * SC;   // scaled domain
        ml[(size_t)(half * 16384 + tok) * 2 + 1] = lsum;
    }
}

// ---------------------------------------------------------------------------
extern "C" void kernel_launch(void* const* d_in, const int* in_sizes, int n_in,
                              void* d_out, int out_size, void* d_ws, size_t ws_size,
                              hipStream_t stream) {
    const float* x      = (const float*)d_in[0];
    const float* gamma  = (const float*)d_in[1];
    const float* w_qkv  = (const float*)d_in[2];
    const float* b_qkv  = (const float*)d_in[3];
    const float* w_proj = (const float*)d_in[4];
    const float* b_proj = (const float*)d_in[5];
    float* out = (float*)d_out;

    // workspace carve (~46 MiB); staging 16B overreads at buffer tails land
    // in the next ws buffer. xn is dead after the qkv gemm -> reused as op0.
    char* ws = (char*)d_ws;
    bf16* xn  = (bf16*)ws;    ws += (size_t)16384 * 384 * 2;   // normalized x / flash partial-0
    uint8_t* qkb = (uint8_t*)ws; ws += (size_t)16384 * 768;    // Q|K fp8, [tok][768]
    uint8_t* vtb = (uint8_t*)ws; ws += (size_t)384 * 16384;    // V^T fp8, [d][tok]
    bf16* ob  = (bf16*)ws;    ws += (size_t)16384 * 384 * 2;   // flash partial-1
    bf16* wqb = (bf16*)ws;    ws += (size_t)1152 * 384 * 2;    // w_qkv bf16
    bf16* wpb = (bf16*)ws;    ws += (size_t)384 * 384 * 2;     // w_proj bf16
    float* mlb = (float*)ws;  ws += (size_t)2 * 16384 * 2 * 4; // m*SC,l per (half, tok)

    // dynamic LDS for flash: 81920B (2 blocks/CU x 80KB = 160KB exactly)
    (void)hipFuncSetAttribute((const void*)flash_kernel,
                              hipFuncAttributeMaxDynamicSharedMemorySize, 81920);

    // norm (blocks 0..255, LDS-transposed coalesced writes) + convert (256..383)
    norm_kernel<<<384, 256, 0, stream>>>(x, gamma, w_qkv, w_proj, xn, wqb, wpb);
    // fused QK fp8 [tok][768] + V^T fp8 [d][tok]
    gemm_qkv<<<1152, 256, 0, stream>>>(xn, wqb, b_qkv, qkb, vtb);
    flash_kernel<<<512, 256, 81920, stream>>>(qkb, vtb, xn, ob, mlb);
    // proj + fused partial-merge + bias + residual, fp32 out
    gemm_proj<<<384, 256, 0, stream>>>(wpb, xn, ob, mlb, b_proj, x, out);
}

// Round 14
// 235.981 us; speedup vs baseline: 1.0293x; 1.0041x over previous
//
#include <hip/hip_runtime.h>
#include <cstdint>
#include <cstddef>

typedef __bf16 bf16;
typedef __bf16 bf16x8 __attribute__((ext_vector_type(8)));
typedef float  f32x4 __attribute__((ext_vector_type(4)));
typedef float  f32x16 __attribute__((ext_vector_type(16)));
typedef int    i32x4 __attribute__((ext_vector_type(4)));
typedef int    i32x8 __attribute__((ext_vector_type(8)));

#define MFMA16(a, b, c) __builtin_amdgcn_mfma_f32_16x16x32_bf16((a), (b), (c), 0, 0, 0)
// MX-scaled fp8 MFMA, both scales = 1.0 (E8M0 127): fmt a=b=0 (fp8 e4m3)
#define MFMA_MX(a, b, c) \
    __builtin_amdgcn_mfma_scale_f32_32x32x64_f8f6f4((a), (b), (c), 0, 0, 0, 0x7F, 0, 0x7F)

#if __has_builtin(__builtin_amdgcn_exp2f)
#define EXP2(x) __builtin_amdgcn_exp2f(x)
#else
#define EXP2(x) exp2f(x)
#endif

// float -> fp8 e4m3 (OCP), RNE, single byte
__device__ __forceinline__ uint8_t to_fp8(float v) {
    return (uint8_t)(__builtin_amdgcn_cvt_pk_fp8_f32(v, v, 0, false) & 0xff);
}

// 32B load as two 16B vector loads (LDS: 2x ds_read_b128; global: 2x dwordx4)
__device__ __forceinline__ i32x8 ld32(const void* p) {
    i32x4 a = *(const i32x4*)p;
    i32x4 b = *(const i32x4*)((const char*)p + 16);
    i32x8 r;
    r[0] = a[0]; r[1] = a[1]; r[2] = a[2]; r[3] = a[3];
    r[4] = b[0]; r[5] = b[1]; r[6] = b[2]; r[7] = b[3];
    return r;
}

// async global->LDS, 16B per lane. LDS dest is wave-uniform base + lane*16.
__device__ __forceinline__ void gload16(const void* g, void* l) {
    __builtin_amdgcn_global_load_lds(
        (const __attribute__((address_space(1))) unsigned int*)g,
        (__attribute__((address_space(3))) unsigned int*)l,
        16, 0, 0);
}

// ---------------------------------------------------------------------------
// RMSNorm + (blocks 256..383) weight fp32->bf16 conversion.
// Blocks 0..255: 64 tokens each; wave w owns channel quarter [96w,96w+96),
// lane l owns token p0+l; values live in registers. Output goes through an
// LDS [64][392] transpose tile so the xn write is fully coalesced.
// x [4][384][4096] fp32 -> xn [16384][384] bf16.
// ---------------------------------------------------------------------------
__global__ __launch_bounds__(256) void norm_kernel(
    const float* __restrict__ x, const float* __restrict__ gamma,
    const float* __restrict__ wqkv, const float* __restrict__ wproj,
    bf16* __restrict__ xn, bf16* __restrict__ wq, bf16* __restrict__ wp)
{
    const int tid = threadIdx.x;
    const int blk = blockIdx.x;
    if (blk >= 256) {
        // weight conversion, grid-stride over 589824 elems (128 blocks)
        int t0 = (blk - 256) * 256 + tid;
        for (int t = t0; t < 1152 * 384 + 384 * 384; t += 128 * 256) {
            if (t < 1152 * 384) wq[t] = (bf16)wqkv[t];
            else                wp[t - 1152 * 384] = (bf16)wproj[t - 1152 * 384];
        }
        return;
    }
    __shared__ float sG[384];
    __shared__ float sS[4][64];
    __shared__ float sScale[64];
    __shared__ bf16  sT[64][392];              // transpose tile, +8 elem pad
    const int w = tid >> 6, l = tid & 63;
    for (int i = tid; i < 384; i += 256) sG[i] = gamma[i];
    const int b = blk >> 6, p0 = (blk & 63) << 6;
    const float* xc = x + ((size_t)(b * 384 + 96 * w)) * 4096 + p0 + l;
    float v[96];
    float s0 = 0.f, s1 = 0.f;
#pragma unroll
    for (int c = 0; c < 96; c += 2) {
        v[c]     = xc[(size_t)c * 4096];
        v[c + 1] = xc[(size_t)(c + 1) * 4096];
        s0 += v[c] * v[c]; s1 += v[c + 1] * v[c + 1];
    }
    sS[w][l] = s0 + s1;
    __syncthreads();
    if (w == 0) {
        float t = (sS[0][l] + sS[1][l]) + (sS[2][l] + sS[3][l]);
        sScale[l] = 19.595917942265423f / fmaxf(sqrtf(t), 1e-12f); // sqrt(384)/max(l2,eps)
    }
    __syncthreads();
    float sc = sScale[l];
    // scale + convert into LDS transpose tile (row = token, cols 96w..96w+96)
#pragma unroll
    for (int c0 = 0; c0 < 96; c0 += 8) {
        bf16x8 v8;
#pragma unroll
        for (int j = 0; j < 8; ++j)
            v8[j] = (bf16)(v[c0 + j] * sc * sG[96 * w + c0 + j]);
        *(bf16x8*)(&sT[l][96 * w + c0]) = v8;
    }
    __syncthreads();
    // coalesced writeout: thread t -> row t>>2, segment t&3 (192B each)
    const int r = tid >> 2, seg = tid & 3;
    const bf16* srow = &sT[r][seg * 96];
    bf16* drow = xn + (size_t)((b << 12) + p0 + r) * 384 + seg * 96;
#pragma unroll
    for (int j = 0; j < 12; ++j)
        *(i32x4*)(drow + j * 8) = *(const i32x4*)(srow + j * 8);
}

// ---------------------------------------------------------------------------
// BT GEMM core: C[m][n] = sum_k A[m][k]*B[n][k], K=384 fixed, tile 128x128.
// mode 0: C fp8 = acc + bias_n[n], ldc given   (QK -> qkb)
// mode 1: C fp8 = acc + bias_m[m], ldc given   (V^T [d][16384] buffer)
// Direct scalar fp8 stores (R12's LDS-epilogue variant regressed ~10us:
// stores were already 64B-runs-per-quad; extra barriers cost more).
// ---------------------------------------------------------------------------
__device__ __forceinline__ void gemm_core_bt(
    bf16* sA, bf16* sB,
    const bf16* __restrict__ A, const bf16* __restrict__ B,
    const float* __restrict__ bias_m, const float* __restrict__ bias_n,
    uint8_t* __restrict__ Cout, const int mode, const int ldc,
    const int m0, const int n0)
{
    const int tid = threadIdx.x;
    const int l = tid & 63, w = tid >> 6;
    const int lo = l & 15, hi = l >> 4;
    const int wm = w >> 1, wn = w & 1;

    f32x4 acc[4][4] = {};

    for (int kt = 0; kt < 6; ++kt) {
        __syncthreads();
        const int k0 = kt * 64;
#pragma unroll
        for (int i = 0; i < 5; ++i) {
            int ci = i * 256 + tid;
            if (ci < 1152) {
                int row = ci / 9, off = ci % 9;  // off==8 loads harmless slack into pad
                gload16(A + (size_t)(m0 + row) * 384 + k0 + off * 8, (char*)sA + ci * 16);
                gload16(B + (size_t)(n0 + row) * 384 + k0 + off * 8, (char*)sB + ci * 16);
            }
        }
        __syncthreads();
#pragma unroll
        for (int ks = 0; ks < 2; ++ks) {
            bf16x8 af[4], bfr[4];
#pragma unroll
            for (int t = 0; t < 4; ++t)
                af[t] = *(const bf16x8*)(sA + (wm * 64 + t * 16 + lo) * 72 + ks * 32 + hi * 8);
#pragma unroll
            for (int t = 0; t < 4; ++t)
                bfr[t] = *(const bf16x8*)(sB + (wn * 64 + t * 16 + lo) * 72 + ks * 32 + hi * 8);
#pragma unroll
            for (int rt = 0; rt < 4; ++rt)
#pragma unroll
                for (int ct = 0; ct < 4; ++ct)
                    acc[rt][ct] = MFMA16(af[rt], bfr[ct], acc[rt][ct]);
        }
    }

    // epilogue: C/D layout col = lo, row = hi*4 + reg
#pragma unroll
    for (int rt = 0; rt < 4; ++rt) {
#pragma unroll
        for (int ct = 0; ct < 4; ++ct) {
            int mb = m0 + wm * 64 + rt * 16 + hi * 4;
            int n  = n0 + wn * 64 + ct * 16 + lo;
            if (mode == 0) {
                float bn = bias_n[n];
#pragma unroll
                for (int r = 0; r < 4; ++r)
                    Cout[(size_t)(mb + r) * ldc + n] = to_fp8(acc[rt][ct][r] + bn);
            } else {
#pragma unroll
                for (int r = 0; r < 4; ++r)
                    Cout[(size_t)(mb + r) * ldc + n] = to_fp8(acc[rt][ct][r] + bias_m[mb + r]);
            }
        }
    }
}

// Fused QKV: blocks [0,768) do QK (M=16384,N=768), [768,1152) do V^T (M=384,N=16384).
// XCD-grouped tile maps (wgid%8 = XCD): QK -> each XCD owns 16 m-tiles (A-panel
// 1.5MB L2-resident); V^T -> each XCD owns 16 n-tiles (B-panel 1.6MB).
__global__ __launch_bounds__(256) void gemm_qkv(
    const bf16* __restrict__ xn, const bf16* __restrict__ wq,
    const float* __restrict__ b_qkv, uint8_t* __restrict__ qkb,
    uint8_t* __restrict__ vtb)
{
    __shared__ bf16 sA[128 * 72];   // 144B rows (128B data + 16B pad)
    __shared__ bf16 sB[128 * 72];
    const int id = blockIdx.x;
    if (id < 768) {
        const int xcd = id & 7, s = id >> 3;       // s in [0,96)
        gemm_core_bt(sA, sB, xn, wq, nullptr, b_qkv, qkb, 0, 768,
                     (xcd * 16 + s / 6) * 128, (s % 6) * 128);
    } else {
        const int t = id - 768;                    // 768%8==0: t&7 == XCD
        const int xcd = t & 7, s = t >> 3;         // s in [0,48)
        gemm_core_bt(sA, sB, wq + (size_t)768 * 384, xn, b_qkv + 768, nullptr,
                     vtb, 1, 16384, (s % 3) * 128, (xcd * 16 + s / 3) * 128);
    }
}

// ---------------------------------------------------------------------------
// Proj GEMM with fused partial-merge: B rows are built on the fly as
// (a0*O0 + a1*O1)/(a0*l0 + a1*l1) from the two flash partials, then
// C = wp @ B^T + b_proj + resid, fp32 out in [b][c][h][w] layout.
// Direct stores (R12's LDS-epilogue variant regressed; reverted).
// 1-D grid 384, XCD-grouped: each XCD owns 16 n-tiles (partials L2-resident).
// ---------------------------------------------------------------------------
__global__ __launch_bounds__(256) void gemm_proj(
    const bf16* __restrict__ wp, const bf16* __restrict__ p0,
    const bf16* __restrict__ p1, const float* __restrict__ ml,
    const float* __restrict__ b_proj, const float* __restrict__ x,
    float* __restrict__ out)
{
    __shared__ bf16 sA[128 * 72];
    __shared__ bf16 sB[128 * 72];
    const int tid = threadIdx.x;
    const int l = tid & 63, w = tid >> 6;
    const int lo = l & 15, hi = l >> 4;
    const int wm = w >> 1, wn = w & 1;
    const int id = blockIdx.x;
    const int xcd = id & 7, s = id >> 3;           // s in [0,48)
    const int m0 = (s % 3) * 128, n0 = (xcd * 16 + s / 3) * 128;

    f32x4 acc[4][4] = {};

    for (int kt = 0; kt < 6; ++kt) {
        __syncthreads();
        const int k0 = kt * 64;
#pragma unroll
        for (int i = 0; i < 5; ++i) {
            int ci = i * 256 + tid;
            if (ci < 1152) {
                int row = ci / 9, off = ci % 9;
                gload16(wp + (size_t)(m0 + row) * 384 + k0 + off * 8, (char*)sA + ci * 16);
                // merged B chunk
                int tok = n0 + row;
                float2 ml0 = *(const float2*)(ml + (size_t)tok * 2);
                float2 ml1 = *(const float2*)(ml + (size_t)(16384 + tok) * 2);
                float mM = fmaxf(ml0.x, ml1.x);
                float a0 = EXP2(ml0.x - mM), a1 = EXP2(ml1.x - mM);
                float inv = 1.0f / (a0 * ml0.y + a1 * ml1.y);
                float w0 = a0 * inv, w1 = a1 * inv;
                size_t boff = (size_t)tok * 384 + k0 + off * 8;  // off==8: slack into pad
                bf16x8 v0 = *(const bf16x8*)(p0 + boff);
                bf16x8 v1 = *(const bf16x8*)(p1 + boff);
                bf16x8 r;
#pragma unroll
                for (int j = 0; j < 8; ++j)
                    r[j] = (bf16)((float)v0[j] * w0 + (float)v1[j] * w1);
                *(bf16x8*)((char*)sB + ci * 16) = r;
            }
        }
        __syncthreads();
#pragma unroll
        for (int ks = 0; ks < 2; ++ks) {
            bf16x8 af[4], bfr[4];
#pragma unroll
            for (int t = 0; t < 4; ++t)
                af[t] = *(const bf16x8*)(sA + (wm * 64 + t * 16 + lo) * 72 + ks * 32 + hi * 8);
#pragma unroll
            for (int t = 0; t < 4; ++t)
                bfr[t] = *(const bf16x8*)(sB + (wn * 64 + t * 16 + lo) * 72 + ks * 32 + hi * 8);
#pragma unroll
            for (int rt = 0; rt < 4; ++rt)
#pragma unroll
                for (int ct = 0; ct < 4; ++ct)
                    acc[rt][ct] = MFMA16(af[rt], bfr[ct], acc[rt][ct]);
        }
    }

#pragma unroll
    for (int rt = 0; rt < 4; ++rt) {
#pragma unroll
        for (int ct = 0; ct < 4; ++ct) {
            int mb = m0 + wm * 64 + rt * 16 + hi * 4;
            int n  = n0 + wn * 64 + ct * 16 + lo;
            int bb = n >> 12, p = n & 4095;
#pragma unroll
            for (int r = 0; r < 4; ++r) {
                int m = mb + r;
                size_t idx = ((size_t)(bb * 384 + m)) * 4096 + p;
                out[idx] = acc[rt][ct][r] + b_proj[m] + x[idx];
            }
        }
    }
}

// ---------------------------------------------------------------------------
// Flash attention (best config + counted-vmcnt barrier A): transposed-S,
// MX-fp8 32x32x64, Bk=64. LDS dynamic 81920B = 2 blocks/CU x 80KB = 160KB:
// K double-buffered 2x[64][400]=51200 + V^T single [384][80]=30720.
// Schedule/iter: {issue V[t] then K[t+1] DMA -> QK+softmax from K[c] ->
// barrier A with vmcnt(6) (drains all V in every wave-count scenario, leaves
// K[t+1] in flight through PV; kt==31 tail uses vmcnt(0)) -> PV from sV ->
// barrier B (full drain: K landed before next QK)}. Hoisted staging offsets.
// qk [16384][768] fp8 (Q|K), vt [384][16384] fp8 (V^T).
// Grid 512: bh = id&7 (one (b,half) per XCD, K/V set 1.5MB L2-resident).
// Online softmax with T13 defer-max (thr 8 in log2 dom; P<=2^8 < fp8 448).
// ---------------------------------------------------------------------------
__global__ __launch_bounds__(256, 2) void flash_kernel(
    const uint8_t* __restrict__ qk, const uint8_t* __restrict__ vt,
    bf16* __restrict__ op0, bf16* __restrict__ op1, float* __restrict__ ml)
{
    extern __shared__ char smem[];             // K bufs @0/25600, V @51200
    uint8_t* sbase = (uint8_t*)smem;
    uint8_t* sV = sbase + 51200;
    const int tid = threadIdx.x;
    const int l = tid & 63, w = tid >> 6;
    const int l31 = l & 31, hi2 = l >> 5;
    const int wq = w >> 1, wd = w & 1;
    const int id = blockIdx.x;
    const int qt = id >> 3, bh = id & 7;       // bh == wgid%8 -> one bh per XCD
    const int b = bh >> 1, half = bh & 1;
    const int q0 = b * 4096 + qt * 64;
    const int kvbase = b * 4096 + half * 2048;
    const float SC = 0.07362217057594547f;     // (1/sqrt(384)) * log2(e)
    const float THR = 108.664f;                // 8 / SC (defer-max threshold)

    // hoisted K staging offsets: 1600 chunks (64 rows x 25; 24 data + 1 pad)
    uint32_t ksrc[7];
#pragma unroll
    for (int i = 0; i < 7; ++i) {
        int ci = i * 256 + tid;
        int row = ci / 25, off = ci % 25;      // off==24 stages slack into pad
        ksrc[i] = (uint32_t)((kvbase + row) * 768 + 384 + off * 16);
    }
    // hoisted V staging offsets: 1920 chunks (384 rows x 5; 4 data + 1 pad)
    uint32_t vsrc[8];
#pragma unroll
    for (int i = 0; i < 8; ++i) {
        int ci = i * 256 + tid;
        int row = ci / 5, off = ci % 5;
        vsrc[i] = (uint32_t)(row * 16384 + kvbase + off * 16);
    }
    // prologue: K[0] into buf 0
#pragma unroll
    for (int i = 0; i < 7; ++i) {
        if (i < 6 || tid < 64) gload16(qk + ksrc[i], sbase + i * 4096 + tid * 16);
        ksrc[i] += 49152;                      // advance one kv-tile (64*768)
    }

    // Q B-frags: lane (l31=q, hi2) holds Q[q0+wq*32+l31][ksw*64 + hi2*32 + j]
    i32x8 qf[6];
    {
        const uint8_t* qrow = qk + (size_t)(q0 + wq * 32 + l31) * 768 + hi2 * 32;
#pragma unroll
        for (int ksw = 0; ksw < 6; ++ksw)
            qf[ksw] = ld32(qrow + ksw * 64);
    }

    f32x16 o[6] = {};    // o[dt]: q=l31, d = wd*192+dt*32+(r&3)+8*(r>>2)+4*hi2
    float m = -1e30f, lsum = 0.f;              // raw-score domain

    __syncthreads();                           // K[0] staged (drains vmcnt)

    int c = 0;                                 // current K buf: byte offset c*25600
    for (int kt = 0; kt < 32; ++kt) {
        // issue V[t] FIRST (oldest in vmcnt order), then K[t+1]
#pragma unroll
        for (int i = 0; i < 8; ++i) {
            if (i < 7 || tid < 128) gload16(vt + vsrc[i], sV + i * 4096 + tid * 16);
            vsrc[i] += 64;
        }
        if (kt < 31) {
            uint8_t* dst = sbase + (c ^ 1) * 25600;
#pragma unroll
            for (int i = 0; i < 7; ++i) {
                if (i < 6 || tid < 64) gload16(qk + ksrc[i], dst + i * 4096 + tid * 16);
                ksrc[i] += 49152;
            }
        }

        // S^T[64kv][32q] as two 32x32 tiles (kvt): A = K rows, B = Q regs
        const uint8_t* sK = sbase + c * 25600;
        f32x16 s0 = {}, s1 = {};
        __builtin_amdgcn_s_setprio(1);
#pragma unroll
        for (int ksw = 0; ksw < 6; ++ksw) {
            i32x8 ak0 = ld32(sK + (size_t)l31 * 400 + ksw * 64 + hi2 * 32);
            i32x8 ak1 = ld32(sK + (size_t)(32 + l31) * 400 + ksw * 64 + hi2 * 32);
            s0 = MFMA_MX(ak0, qf[ksw], s0);
            s1 = MFMA_MX(ak1, qf[ksw], s1);
        }
        __builtin_amdgcn_s_setprio(0);

        // online softmax: lane holds 32 kv (own hi2 blocks) for q=l31
        float a0 = fmaxf(fmaxf(s0[0],  s0[1]),  fmaxf(s0[2],  s0[3]));
        float a1 = fmaxf(fmaxf(s0[4],  s0[5]),  fmaxf(s0[6],  s0[7]));
        float a2 = fmaxf(fmaxf(s0[8],  s0[9]),  fmaxf(s0[10], s0[11]));
        float a3 = fmaxf(fmaxf(s0[12], s0[13]), fmaxf(s0[14], s0[15]));
        float b0 = fmaxf(fmaxf(s1[0],  s1[1]),  fmaxf(s1[2],  s1[3]));
        float b1 = fmaxf(fmaxf(s1[4],  s1[5]),  fmaxf(s1[6],  s1[7]));
        float b2 = fmaxf(fmaxf(s1[8],  s1[9]),  fmaxf(s1[10], s1[11]));
        float b3 = fmaxf(fmaxf(s1[12], s1[13]), fmaxf(s1[14], s1[15]));
        float mx = fmaxf(fmaxf(fmaxf(a0, a1), fmaxf(a2, a3)),
                         fmaxf(fmaxf(b0, b1), fmaxf(b2, b3)));
        mx = fmaxf(mx, __shfl_xor(mx, 32));
        if (__any(mx > m + THR)) {             // T13: rare (first iter + big jumps)
            float mn = fmaxf(m, mx);
            float alpha = EXP2((m - mn) * SC);
            m = mn;
            lsum *= alpha;
#pragma unroll
            for (int dt = 0; dt < 6; ++dt)
#pragma unroll
                for (int r = 0; r < 16; ++r) o[dt][r] *= alpha;
        }
        float p0[16], p1[16];
        float msc = m * SC;
        float rsa = 0.f, rsb = 0.f, rsc = 0.f, rsd = 0.f;
#pragma unroll
        for (int r = 0; r < 16; r += 4) {
            p0[r]     = EXP2(fmaf(s0[r],     SC, -msc)); rsa += p0[r];
            p0[r + 1] = EXP2(fmaf(s0[r + 1], SC, -msc)); rsb += p0[r + 1];
            p0[r + 2] = EXP2(fmaf(s0[r + 2], SC, -msc)); rsc += p0[r + 2];
            p0[r + 3] = EXP2(fmaf(s0[r + 3], SC, -msc)); rsd += p0[r + 3];
        }
#pragma unroll
        for (int r = 0; r < 16; r += 4) {
            p1[r]     = EXP2(fmaf(s1[r],     SC, -msc)); rsa += p1[r];
            p1[r + 1] = EXP2(fmaf(s1[r + 1], SC, -msc)); rsb += p1[r + 1];
            p1[r + 2] = EXP2(fmaf(s1[r + 2], SC, -msc)); rsc += p1[r + 2];
            p1[r + 3] = EXP2(fmaf(s1[r + 3], SC, -msc)); rsd += p1[r + 3];
        }
        float rs = (rsa + rsb) + (rsc + rsd);
        rs += __shfl_xor(rs, 32);
        lsum += rs;

        // pack P to fp8 dwords. s-reg r of kvt holds kv = kvt*32+(r&3)+8*(r>>2)+4*hi2.
        // own pk dword i = kv {kvt*32 + 8i + 4*hi2 .. +3}. B-frag (this lane) needs
        // kv {hi2*32 + j}: kvt = hi2, interleave own/partner(xor32) dwords.
        int pk0[4], pk1[4];
#pragma unroll
        for (int i = 0; i < 4; ++i) {
            int d = __builtin_amdgcn_cvt_pk_fp8_f32(p0[4 * i], p0[4 * i + 1], 0, false);
            pk0[i] = __builtin_amdgcn_cvt_pk_fp8_f32(p0[4 * i + 2], p0[4 * i + 3], d, true);
            d = __builtin_amdgcn_cvt_pk_fp8_f32(p1[4 * i], p1[4 * i + 1], 0, false);
            pk1[i] = __builtin_amdgcn_cvt_pk_fp8_f32(p1[4 * i + 2], p1[4 * i + 3], d, true);
        }
        i32x8 pf;
#pragma unroll
        for (int i = 0; i < 4; ++i) {
            int x0 = __shfl_xor(pk0[i], 32);   // partner's kvt=0 dword
            int x1 = __shfl_xor(pk1[i], 32);   // partner's kvt=1 dword
            int own = hi2 ? pk1[i] : pk0[i];
            int oth = hi2 ? x1 : x0;
            pf[2 * i]     = hi2 ? oth : own;   // kv 8i+0..3 (rel. to hi2*32)
            pf[2 * i + 1] = hi2 ? own : oth;   // kv 8i+4..7
        }

        // barrier A: counted wait -- drains all V chunks (issued first) in every
        // wave-count scenario; K[t+1] (6-7 chunks) stays in flight through PV.
        if (kt < 31) {
            asm volatile("s_waitcnt vmcnt(6)" ::: "memory");
        } else {
            asm volatile("s_waitcnt vmcnt(0)" ::: "memory");
        }
        __builtin_amdgcn_sched_barrier(0);
        __builtin_amdgcn_s_barrier();

        // O^T[d][q] += V^T · P^T  (A: V^T rows m=d, k = kv = hi2*32+j, K=64)
        __builtin_amdgcn_s_setprio(1);
#pragma unroll
        for (int dt = 0; dt < 6; ++dt) {
            i32x8 av = ld32(sV + (size_t)(wd * 192 + dt * 32 + l31) * 80 + hi2 * 32);
            o[dt] = MFMA_MX(av, pf, o[dt]);
        }
        __builtin_amdgcn_s_setprio(0);

        __syncthreads();                       // B: full drain -- K[t+1] landed,
                                               // sV reads done before next overwrite
        c ^= 1;
    }

    // epilogue: per-wave O^T -> O transpose through LDS (disjoint 4608B/wave)
    float* tr = (float*)(smem + w * 4608);     // [32 q][36 pitch] fp32
    bf16* dst = half ? op1 : op0;
#pragma unroll
    for (int dt = 0; dt < 6; ++dt) {
#pragma unroll
        for (int r = 0; r < 16; ++r) {
            int d32 = (r & 3) + 8 * (r >> 2) + 4 * hi2;
            tr[l31 * 36 + d32] = o[dt][r];
        }
        f32x4 v0 = *(f32x4*)(tr + l31 * 36 + hi2 * 16 + 0);
        f32x4 v1 = *(f32x4*)(tr + l31 * 36 + hi2 * 16 + 4);
        f32x4 v2 = *(f32x4*)(tr + l31 * 36 + hi2 * 16 + 8);
        f32x4 v3 = *(f32x4*)(tr + l31 * 36 + hi2 * 16 + 12);
        bf16x8 h0, h1;
#pragma unroll
        for (int j = 0; j < 4; ++j) {
            h0[j] = (bf16)v0[j]; h0[4 + j] = (bf16)v1[j];
            h1[j] = (bf16)v2[j]; h1[4 + j] = (bf16)v3[j];
        }
        size_t tok = (size_t)(q0 + wq * 32 + l31);
        bf16* drow = dst + tok * 384 + wd * 192 + dt * 32 + hi2 * 16;
        *(bf16x8*)(drow + 0) = h0;
        *(bf16x8*)(drow + 8) = h1;
    }
    if (wd == 0 && hi2 == 0) {
        int tok = q0 + wq * 32 + l31;
        ml[(size_t)(half * 16384 + tok) * 2 + 0] = m * SC;   // scaled domain
        ml[(size_t)(half * 16384 + tok) * 2 + 1] = lsum;
    }
}

// ---------------------------------------------------------------------------
extern "C" void kernel_launch(void* const* d_in, const int* in_sizes, int n_in,
                              void* d_out, int out_size, void* d_ws, size_t ws_size,
                              hipStream_t stream) {
    const float* x      = (const float*)d_in[0];
    const float* gamma  = (const float*)d_in[1];
    const float* w_qkv  = (const float*)d_in[2];
    const float* b_qkv  = (const float*)d_in[3];
    const float* w_proj = (const float*)d_in[4];
    const float* b_proj = (const float*)d_in[5];
    float* out = (float*)d_out;

    // workspace carve (~46 MiB); staging 16B overreads at buffer tails land
    // in the next ws buffer. xn is dead after the qkv gemm -> reused as op0.
    char* ws = (char*)d_ws;
    bf16* xn  = (bf16*)ws;    ws += (size_t)16384 * 384 * 2;   // normalized x / flash partial-0
    uint8_t* qkb = (uint8_t*)ws; ws += (size_t)16384 * 768;    // Q|K fp8, [tok][768]
    uint8_t* vtb = (uint8_t*)ws; ws += (size_t)384 * 16384;    // V^T fp8, [d][tok]
    bf16* ob  = (bf16*)ws;    ws += (size_t)16384 * 384 * 2;   // flash partial-1
    bf16* wqb = (bf16*)ws;    ws += (size_t)1152 * 384 * 2;    // w_qkv bf16
    bf16* wpb = (bf16*)ws;    ws += (size_t)384 * 384 * 2;     // w_proj bf16
    float* mlb = (float*)ws;  ws += (size_t)2 * 16384 * 2 * 4; // m*SC,l per (half, tok)

    // dynamic LDS for flash: 81920B (2 blocks/CU x 80KB = 160KB exactly)
    (void)hipFuncSetAttribute((const void*)flash_kernel,
                              hipFuncAttributeMaxDynamicSharedMemorySize, 81920);

    // norm (blocks 0..255, LDS-transposed coalesced writes) + convert (256..383)
    norm_kernel<<<384, 256, 0, stream>>>(x, gamma, w_qkv, w_proj, xn, wqb, wpb);
    // fused QK fp8 [tok][768] + V^T fp8 [d][tok]
    gemm_qkv<<<1152, 256, 0, stream>>>(xn, wqb, b_qkv, qkb, vtb);
    flash_kernel<<<512, 256, 81920, stream>>>(qkb, vtb, xn, ob, mlb);
    // proj + fused partial-merge + bias + residual, fp32 out
    gemm_proj<<<384, 256, 0, stream>>>(wpb, xn, ob, mlb, b_proj, x, out);
}